// Round 2
// baseline (275.283 us; speedup 1.0000x reference)
//
#include <hip/hip_runtime.h>

// CCE loss reduction: out[0] = -sum(input * log(target + 1e-8)) / B
// B = 262144, C = 128, f32 inputs. Streaming reduction, memory-bound.
//
// History:
//  R1: simple grid-stride float4, VGPR=12, 2.6 TB/s eff (latency-bound).
//  R2: 4x batch unroll -> SAME 2.6 TB/s, VGPR=32. The compiler rolled the
//      batch back into serialized load->wait->consume pairs; nominal MLP
//      never reached the hardware. VALUBusy 12.6%, HBM 16-40% => idle machine.
//  R3: forced MLP via named double-buffer pipeline. Bench infra failed
//      twice before launch -> no data. This is the R3 retry, unchanged.
//      Depth-1 software pipeline with NAMED double buffers (8 dwordx4
//      loads live across the whole compute phase), sched_barrier(0) to
//      pin the load cluster, launch_bounds(256,4) -> 128 VGPR budget,
//      GRID=1024 (exactly 4 blocks/CU).
//      Target: ~8KB in flight/wave, 128KB/CU -> saturate the read path.

constexpr int BLOCK = 256;
constexpr int GRID  = 1024;  // 4 blocks/CU x 256 CUs, VGPR-safe at <=128

__global__ __launch_bounds__(BLOCK, 4) void cce_reduce_kernel(
    const float* __restrict__ inp, const float* __restrict__ tgt,
    float* __restrict__ out, int n4, float neg_inv_b) {
  const float4* __restrict__ in4 = reinterpret_cast<const float4*>(inp);
  const float4* __restrict__ tg4 = reinterpret_cast<const float4*>(tgt);

  const int idx    = blockIdx.x * BLOCK + threadIdx.x;
  const int stride = GRID * BLOCK;   // 262144 float4 = 4 MiB hop
  const int step   = 4 * stride;

  // 4 independent accumulator chains.
  float acc0 = 0.f, acc1 = 0.f, acc2 = 0.f, acc3 = 0.f;

#define TERM4(X, Y)                        \
  acc0 += (X).x * __logf((Y).x + 1e-8f);   \
  acc1 += (X).y * __logf((Y).y + 1e-8f);   \
  acc2 += (X).z * __logf((Y).z + 1e-8f);   \
  acc3 += (X).w * __logf((Y).w + 1e-8f);

  int i = idx;
  if (i + 7 * stride < n4) {  // at least 2 full batches -> pipeline
    // Prologue: batch 0 into the 'a' buffer.
    float4 ax0 = in4[i],              ay0 = tg4[i];
    float4 ax1 = in4[i + stride],     ay1 = tg4[i + stride];
    float4 ax2 = in4[i + 2 * stride], ay2 = tg4[i + 2 * stride];
    float4 ax3 = in4[i + 3 * stride], ay3 = tg4[i + 3 * stride];
    i += step;

    // Steady state: issue batch k+1 (8 loads, ~8KB) -> compute batch k.
    // The b->a copies at the bottom are the only uses of the b loads, so
    // s_waitcnt lands AFTER the compute: loads stay in flight across TERM4.
    for (; i + 3 * stride < n4; i += step) {
      float4 bx0 = in4[i],              by0 = tg4[i];
      float4 bx1 = in4[i + stride],     by1 = tg4[i + stride];
      float4 bx2 = in4[i + 2 * stride], by2 = tg4[i + 2 * stride];
      float4 bx3 = in4[i + 3 * stride], by3 = tg4[i + 3 * stride];
      // Pin the load cluster: nothing may be scheduled across this point,
      // so the compiler cannot sink loads down into the compute to shrink
      // register pressure (what it did to R2).
      __builtin_amdgcn_sched_barrier(0);

      TERM4(ax0, ay0) TERM4(ax1, ay1) TERM4(ax2, ay2) TERM4(ax3, ay3)

      ax0 = bx0; ay0 = by0; ax1 = bx1; ay1 = by1;
      ax2 = bx2; ay2 = by2; ax3 = bx3; ay3 = by3;
    }
    // Epilogue: compute the last prefetched batch.
    TERM4(ax0, ay0) TERM4(ax1, ay1) TERM4(ax2, ay2) TERM4(ax3, ay3)
  }
  // Generic tail (not taken for 262144x128 with this GRID, but keep general).
  for (; i < n4; i += stride) {
    float4 x = in4[i], y = tg4[i];
    TERM4(x, y)
  }
#undef TERM4

  float acc = (acc0 + acc1) + (acc2 + acc3);

  // wave-64 shuffle reduction
  #pragma unroll
  for (int off = 32; off > 0; off >>= 1)
    acc += __shfl_down(acc, off, 64);

  __shared__ float s[BLOCK / 64];
  const int lane = threadIdx.x & 63;
  const int wave = threadIdx.x >> 6;
  if (lane == 0) s[wave] = acc;
  __syncthreads();

  if (threadIdx.x == 0) {
    float t = 0.0f;
    #pragma unroll
    for (int w = 0; w < BLOCK / 64; ++w) t += s[w];
    atomicAdd(out, t * neg_inv_b);  // one device-scope atomic per block
  }
}

extern "C" void kernel_launch(void* const* d_in, const int* in_sizes, int n_in,
                              void* d_out, int out_size, void* d_ws, size_t ws_size,
                              hipStream_t stream) {
  const float* inp = reinterpret_cast<const float*>(d_in[0]);
  const float* tgt = reinterpret_cast<const float*>(d_in[1]);
  float* out = reinterpret_cast<float*>(d_out);

  const long long n = (long long)in_sizes[0];  // 262144 * 128
  const int n4 = (int)(n / 4);                 // exactly divisible (128 cols)
  const long long B = 262144;                  // rows, per reference
  const float neg_inv_b = -1.0f / (float)B;

  // d_out is re-poisoned to 0xAA before every timed launch -> zero it here.
  hipMemsetAsync(d_out, 0, out_size * sizeof(float), stream);

  cce_reduce_kernel<<<GRID, BLOCK, 0, stream>>>(inp, tgt, out, n4, neg_inv_b);
}

// Round 3
// 255.971 us; speedup vs baseline: 1.0754x; 1.0754x over previous
//
#include <hip/hip_runtime.h>

// CCE loss reduction: out[0] = -sum(input * log(target + 1e-8)) / B
// B = 262144, C = 128, f32 inputs. Streaming reduction, memory-bound.
//
// History:
//  R1: grid-stride float4, VGPR=12 -> 2.6 TB/s (latency-bound).
//  R2: 4x batch unroll, VGPR=32, GRID=2048 -> 2.6 TB/s, 103 us. Compiler
//      serialized the batch; MLP never materialized.
//  R3: named double-buffer pipeline + sched_barrier, GRID=1024 -> VGPR=48
//      (pipeline REAL: 1 live + 1 in-flight batch), 98 us, 2.74 TB/s.
//      2x per-CU outstanding bytes vs R2 bought only +5% -> wave MLP is no
//      longer the limiter; a per-CU fill-path resource (L1 line alloc /
//      miss queue) or the die read fabric is.
//  R4 (this): attack the fill path.
//      a) NONTEMPORAL loads: 268 MB single-use stream; stop allocating L1
//         lines / burning L1 fill machinery for zero hits (nt flag).
//      b) GRID back to 2048 (8 blocks/CU resident at VGPR<=64): 32 waves/CU
//         x 8KB in flight = 256 KB/CU demand, 2x R3.
//      If dur stays ~98 us after BOTH, the ~2.7 TB/s read-path cap is
//      structural and we are at roofline for this access pattern.

typedef float f32x4 __attribute__((ext_vector_type(4)));

constexpr int BLOCK = 256;
constexpr int GRID  = 2048;  // 8 blocks/CU x 256 CUs

__global__ __launch_bounds__(BLOCK, 4) void cce_reduce_kernel(
    const float* __restrict__ inp, const float* __restrict__ tgt,
    float* __restrict__ out, int n4, float neg_inv_b) {
  const f32x4* __restrict__ in4 = reinterpret_cast<const f32x4*>(inp);
  const f32x4* __restrict__ tg4 = reinterpret_cast<const f32x4*>(tgt);

  const int idx    = blockIdx.x * BLOCK + threadIdx.x;
  const int stride = GRID * BLOCK;
  const int step   = 4 * stride;

  // 4 independent accumulator chains.
  float acc0 = 0.f, acc1 = 0.f, acc2 = 0.f, acc3 = 0.f;

#define NTL(P) __builtin_nontemporal_load(P)
#define TERM4(X, Y)                          \
  acc0 += (X)[0] * __logf((Y)[0] + 1e-8f);   \
  acc1 += (X)[1] * __logf((Y)[1] + 1e-8f);   \
  acc2 += (X)[2] * __logf((Y)[2] + 1e-8f);   \
  acc3 += (X)[3] * __logf((Y)[3] + 1e-8f);

  int i = idx;
  if (i + 7 * stride < n4) {  // at least 2 full batches -> pipeline
    // Prologue: batch 0 into the 'a' buffer.
    f32x4 ax0 = NTL(in4 + i),              ay0 = NTL(tg4 + i);
    f32x4 ax1 = NTL(in4 + i + stride),     ay1 = NTL(tg4 + i + stride);
    f32x4 ax2 = NTL(in4 + i + 2 * stride), ay2 = NTL(tg4 + i + 2 * stride);
    f32x4 ax3 = NTL(in4 + i + 3 * stride), ay3 = NTL(tg4 + i + 3 * stride);
    i += step;

    // Steady state: issue batch k+1 (8 nt loads, 8KB/wave) -> compute batch k.
    for (; i + 3 * stride < n4; i += step) {
      f32x4 bx0 = NTL(in4 + i),              by0 = NTL(tg4 + i);
      f32x4 bx1 = NTL(in4 + i + stride),     by1 = NTL(tg4 + i + stride);
      f32x4 bx2 = NTL(in4 + i + 2 * stride), by2 = NTL(tg4 + i + 2 * stride);
      f32x4 bx3 = NTL(in4 + i + 3 * stride), by3 = NTL(tg4 + i + 3 * stride);
      // Pin the load cluster: the compiler may not sink loads into the
      // compute to shrink register pressure (R2's failure mode).
      __builtin_amdgcn_sched_barrier(0);

      TERM4(ax0, ay0) TERM4(ax1, ay1) TERM4(ax2, ay2) TERM4(ax3, ay3)

      ax0 = bx0; ay0 = by0; ax1 = bx1; ay1 = by1;
      ax2 = bx2; ay2 = by2; ax3 = bx3; ay3 = by3;
    }
    // Epilogue: compute the last prefetched batch.
    TERM4(ax0, ay0) TERM4(ax1, ay1) TERM4(ax2, ay2) TERM4(ax3, ay3)
  }
  // Generic tail (not taken for 262144x128 with this GRID, but keep general).
  for (; i < n4; i += stride) {
    f32x4 x = NTL(in4 + i), y = NTL(tg4 + i);
    TERM4(x, y)
  }
#undef TERM4
#undef NTL

  float acc = (acc0 + acc1) + (acc2 + acc3);

  // wave-64 shuffle reduction
  #pragma unroll
  for (int off = 32; off > 0; off >>= 1)
    acc += __shfl_down(acc, off, 64);

  __shared__ float s[BLOCK / 64];
  const int lane = threadIdx.x & 63;
  const int wave = threadIdx.x >> 6;
  if (lane == 0) s[wave] = acc;
  __syncthreads();

  if (threadIdx.x == 0) {
    float t = 0.0f;
    #pragma unroll
    for (int w = 0; w < BLOCK / 64; ++w) t += s[w];
    atomicAdd(out, t * neg_inv_b);  // one device-scope atomic per block
  }
}

extern "C" void kernel_launch(void* const* d_in, const int* in_sizes, int n_in,
                              void* d_out, int out_size, void* d_ws, size_t ws_size,
                              hipStream_t stream) {
  const float* inp = reinterpret_cast<const float*>(d_in[0]);
  const float* tgt = reinterpret_cast<const float*>(d_in[1]);
  float* out = reinterpret_cast<float*>(d_out);

  const long long n = (long long)in_sizes[0];  // 262144 * 128
  const int n4 = (int)(n / 4);                 // exactly divisible (128 cols)
  const long long B = 262144;                  // rows, per reference
  const float neg_inv_b = -1.0f / (float)B;

  // d_out is re-poisoned to 0xAA before every timed launch -> zero it here.
  hipMemsetAsync(d_out, 0, out_size * sizeof(float), stream);

  cce_reduce_kernel<<<GRID, BLOCK, 0, stream>>>(inp, tgt, out, n4, neg_inv_b);
}